// Round 20
// baseline (651.609 us; speedup 1.0000x reference)
//
#include <hip/hip_runtime.h>
#include <hip/hip_bf16.h>
#include <cstddef>

// Problem constants
#define BB   8
#define CIN  16
#define COUT 16
#define TT   32
#define HH   16
#define WW   16
#define DIN  4096
#define DOUT 4096
#define NH   4
#define DH   1024
#define SPAT 8192            // T*H*W
#define NSEQ 256             // B*T

typedef __attribute__((ext_vector_type(8))) short  bf16x8;
typedef __attribute__((ext_vector_type(4))) float  f32x4;
typedef __attribute__((ext_vector_type(4))) unsigned short us4;
typedef __attribute__((ext_vector_type(4))) int    i32x4;
typedef unsigned short ushort_t;
typedef unsigned long long u64_t;

static __device__ __forceinline__ ushort_t f2bf(float f) {
    union { float f; unsigned u; } v; v.f = f;
    unsigned r = (v.u + 0x7fffu + ((v.u >> 16) & 1u)) >> 16;
    return (ushort_t)r;
}
static __device__ __forceinline__ float bf2f(ushort_t u) {
    union { unsigned u; float f; } v; v.u = ((unsigned)u) << 16;
    return v.f;
}

// ---------------------------------------------------------------------------
// setup: pack x -> xt (bf16 seq layout) | pack 3 conv weight sets | zero flags
// grid 1114 blocks x 256
// ---------------------------------------------------------------------------
__global__ void setup_kernel(const float* __restrict__ x, ushort_t* __restrict__ xt,
                             const float* __restrict__ w1, const float* __restrict__ w2,
                             const float* __restrict__ w3,
                             float* __restrict__ cw1, float* __restrict__ cw2,
                             float* __restrict__ cw3, int* __restrict__ flags) {
    int bid = blockIdx.x;
    if (bid < 1024) {
        int idx = bid * 256 + threadIdx.x;
        int n = idx >> 10, k4 = (idx & 1023) * 4;
        int b = n >> 5, t = n & 31, c = k4 >> 8, hw = k4 & 255;
        f32x4 f = *(const f32x4*)&x[(((size_t)(b * CIN + c) * TT + t)) * 256 + hw];
        us4 o;
        #pragma unroll
        for (int i = 0; i < 4; ++i) o[i] = f2bf(f[i]);
        *(us4*)&xt[(size_t)n * DIN + k4] = o;
    } else if (bid < 1105) {
        int i = (bid - 1024) * 256 + threadIdx.x;
        if (i < 3 * 6912) {
            int set = i / 6912, j = i - set * 6912;
            const float* w = (set == 0) ? w1 : (set == 1) ? w2 : w3;
            float* cw      = (set == 0) ? cw1 : (set == 1) ? cw2 : cw3;
            int o = j & 15, r = j >> 4;
            int k = r % 27, ci = r / 27;
            cw[j] = w[(size_t)(o * CIN + ci) * 27 + k];
        }
    } else {
        int j = (bid - 1105) * 256 + threadIdx.x;   // int4 each
        if (j < 2241)   // 8192 persist + 512 conv + 256 gx + 1 c3done (+pad)
            ((i32x4*)flags)[j] = (i32x4){0, 0, 0, 0};
    }
}

// ---------------------------------------------------------------------------
// GEMM body (device fn, dynamic LDS): C[256][N] = A[256][K](bf16) * B^T(fp32)
// BM=256, BN/BK template; 4 waves, dbuf. Full K. Optional agent-atomic C.
// ---------------------------------------------------------------------------
template<int BN, int BK, bool OUT_BF16, bool ATOMIC_OUT>
__device__ __forceinline__
void gemm_body(char* smem, int bx,
               const ushort_t* __restrict__ A, const float* __restrict__ B,
               const float* __restrict__ bias, void* __restrict__ C,
               int N, int K) {
    constexpr int NF  = BN / 16;
    constexpr int TPR = 256 / BN;
    constexpr int FPT = BK / TPR;
    ushort_t* Al = (ushort_t*)smem;                 // [2][256][BK]
    ushort_t* Bl = Al + 2 * 256 * BK;               // [2][BN][BK]
    int tid  = threadIdx.x;
    int lane = tid & 63;
    int wv   = tid >> 6;
    int n0 = bx * BN;

    f32x4 acc[4][NF];
    #pragma unroll
    for (int i = 0; i < 4; ++i)
        #pragma unroll
        for (int j = 0; j < NF; ++j) acc[i][j] = (f32x4){0.f, 0.f, 0.f, 0.f};

    auto stageA = [&](int buf, int k0) {
        #pragma unroll
        for (int q = 0; q < 8; ++q) {
            int rbase = wv * 64 + q * 8;
            int row = rbase + (lane >> 3);
            const ushort_t* g = A + (size_t)row * K + k0 + (lane & 7) * 8;
            __builtin_amdgcn_global_load_lds(
                (const __attribute__((address_space(1))) void*)g,
                (__attribute__((address_space(3))) void*)&Al[(buf * 256 + rbase) * BK],
                16, 0, 0);
        }
    };
    auto stageB = [&](int buf, int k0) {
        int r  = tid / TPR;
        int cs = (tid % TPR) * FPT;
        const float* g = B + (size_t)(n0 + r) * K + k0 + cs;
        #pragma unroll
        for (int q = 0; q < FPT / 4; ++q) {
            f32x4 f = *(const f32x4*)(g + q * 4);
            us4 pk;
            #pragma unroll
            for (int e = 0; e < 4; ++e) pk[e] = f2bf(f[e]);
            *(us4*)&Bl[(buf * BN + r) * BK + cs + q * 4] = pk;
        }
    };
    auto compute = [&](int buf) {
        #pragma unroll
        for (int ks = 0; ks < BK / 32; ++ks) {
            bf16x8 af[4], bfr[NF];
            #pragma unroll
            for (int i = 0; i < 4; ++i)
                af[i] = *(const bf16x8*)&Al[(buf * 256 + wv * 64 + i * 16 + (lane & 15)) * BK + ks * 32 + (lane >> 4) * 8];
            #pragma unroll
            for (int j = 0; j < NF; ++j)
                bfr[j] = *(const bf16x8*)&Bl[(buf * BN + j * 16 + (lane & 15)) * BK + ks * 32 + (lane >> 4) * 8];
            #pragma unroll
            for (int i = 0; i < 4; ++i)
                #pragma unroll
                for (int j = 0; j < NF; ++j)
                    acc[i][j] = __builtin_amdgcn_mfma_f32_16x16x32_bf16(af[i], bfr[j], acc[i][j], 0, 0, 0);
        }
    };

    stageA(0, 0); stageB(0, 0);
    __syncthreads();
    int nk = K / BK;
    int cur = 0;
    for (int t = 0; t < nk; ++t) {
        if (t + 1 < nk) { stageA(cur ^ 1, (t + 1) * BK); stageB(cur ^ 1, (t + 1) * BK); }
        compute(cur);
        __syncthreads();
        cur ^= 1;
    }

    #pragma unroll
    for (int i = 0; i < 4; ++i) {
        int row = wv * 64 + i * 16 + (lane >> 4) * 4;
        #pragma unroll
        for (int j = 0; j < NF; ++j) {
            int col = n0 + j * 16 + (lane & 15);
            float bv = bias[col];
            #pragma unroll
            for (int r = 0; r < 4; ++r) {
                float v = acc[i][j][r] + bv;
                if constexpr (OUT_BF16)
                    ((ushort_t*)C)[(size_t)(row + r) * N + col] = f2bf(v);
                else if constexpr (ATOMIC_OUT)
                    __hip_atomic_store(&((float*)C)[(size_t)(row + r) * N + col], v,
                                       __ATOMIC_RELAXED, __HIP_MEMORY_SCOPE_AGENT);
                else
                    ((float*)C)[(size_t)(row + r) * N + col] = v;
            }
        }
    }
}

// ---------------------------------------------------------------------------
// conv tap loop (shared)
// ---------------------------------------------------------------------------
__device__ __forceinline__
void conv_taps(const float* xin, const float* __restrict__ cw, int half,
               const float* __restrict__ bias, float* accs, int tid) {
    int h = tid >> 4, wx = tid & 15;
    f32x4 a0 = *(const f32x4*)&bias[half * 8];
    f32x4 a1 = *(const f32x4*)&bias[half * 8 + 4];
    for (int ci = 0; ci < CIN; ++ci) {
        #pragma unroll
        for (int kt = 0; kt < 3; ++kt) {
            #pragma unroll
            for (int kh = 0; kh < 3; ++kh) {
                int h2 = h + kh - 1;
                bool vh = (unsigned)h2 < HH;
                int h2c = vh ? h2 : 0;
                #pragma unroll
                for (int kw = 0; kw < 3; ++kw) {
                    int w2 = wx + kw - 1;
                    bool v = vh && ((unsigned)w2 < WW);
                    int w2c = ((unsigned)w2 < WW) ? w2 : 0;
                    float xv = xin[(ci * 3 + kt) * 256 + h2c * 16 + w2c];
                    xv = v ? xv : 0.f;
                    const float* wp = cw + (size_t)(ci * 27 + kt * 9 + kh * 3 + kw) * 16 + half * 8;
                    f32x4 w0 = *(const f32x4*)(wp);
                    f32x4 w1 = *(const f32x4*)(wp + 4);
                    a0 += xv * w0; a1 += xv * w1;
                }
            }
        }
    }
    #pragma unroll
    for (int i = 0; i < 4; ++i) { accs[i] = a0[i]; accs[4 + i] = a1[i]; }
}

// ---------------------------------------------------------------------------
// conv1 body: plain loads/stores + psum emission
// ---------------------------------------------------------------------------
__device__ __forceinline__
void conv1_body(char* smem, int blk,
                const float* __restrict__ in, const float* __restrict__ cw,
                const float* __restrict__ bias,
                float* __restrict__ out, float* __restrict__ psum) {
    float* xin = (float*)smem;
    int b = blk >> 6, t = (blk >> 1) & 31, half = blk & 1;
    int tid = threadIdx.x;

    for (int i = tid; i < CIN * 3 * 256; i += 256) {
        int hw = i & 255, r = i >> 8;
        int kt = r % 3, ci = r / 3;
        int tt = t + kt - 1;
        float v = 0.f;
        if ((unsigned)tt < TT)
            v = in[((size_t)(b * CIN + ci) * TT + tt) * 256 + hw];
        xin[(ci * 3 + kt) * 256 + hw] = v;
    }
    __syncthreads();

    float accs[8];
    conv_taps(xin, cw, half, bias, accs, tid);
    #pragma unroll
    for (int o = 0; o < 8; ++o)
        out[((size_t)(b * COUT + half * 8 + o) * TT + t) * 256 + tid] = accs[o];

    __syncthreads();
    float* sm = xin;
    int wv = tid >> 6;
    #pragma unroll
    for (int o = 0; o < 8; ++o) {
        float s = accs[o];
        float q = accs[o] * accs[o];
        #pragma unroll
        for (int m = 1; m < 64; m <<= 1) {
            s += __shfl_xor(s, m, 64);
            q += __shfl_xor(q, m, 64);
        }
        if ((tid & 63) == 0) { sm[wv * 16 + o * 2] = s; sm[wv * 16 + o * 2 + 1] = q; }
    }
    __syncthreads();
    if (tid < 16) {
        int o = tid >> 1, which = tid & 1;
        float v = sm[o * 2 + which] + sm[16 + o * 2 + which]
                + sm[32 + o * 2 + which] + sm[48 + o * 2 + which];
        psum[((((size_t)(b * 32 + t) * 2 + half) * 8 + o) * 2) + which] = v;
    }
}

// ---------------------------------------------------------------------------
// conv2 body: in-block stats from psum, inorm+relu at staging, ATOMIC y2
// stores + per-(b,t,half) flag signal.
// ---------------------------------------------------------------------------
__device__ __forceinline__
void conv2_body(char* smem, int blk,
                const float* __restrict__ y1, const float* __restrict__ cw,
                const float* __restrict__ bias, const float* __restrict__ psum,
                float* __restrict__ y2, int* __restrict__ cflags) {
    float* xin = (float*)smem;              // 12288 floats
    float* sstats = xin + 12288;            // 32 floats
    int b = blk >> 6, t = (blk >> 1) & 31, half = blk & 1;
    int tid = threadIdx.x;

    if (tid < 16) {
        int c = tid;
        float sum = 0.f, sq = 0.f;
        for (int t2 = 0; t2 < 32; ++t2) {
            size_t base = (((size_t)(b * 32 + t2) * 2 + (c >> 3)) * 8 + (c & 7)) * 2;
            sum += psum[base];
            sq  += psum[base + 1];
        }
        float mu = sum / (float)SPAT;
        float var = sq / (float)SPAT - mu * mu;
        sstats[c * 2]     = mu;
        sstats[c * 2 + 1] = rsqrtf(var + 1e-5f);
    }
    __syncthreads();

    for (int i = tid; i < CIN * 3 * 256; i += 256) {
        int hw = i & 255, r = i >> 8;
        int kt = r % 3, ci = r / 3;
        int tt = t + kt - 1;
        float v = 0.f;
        if ((unsigned)tt < TT) {
            v = y1[((size_t)(b * CIN + ci) * TT + tt) * 256 + hw];
            v = fmaxf((v - sstats[ci * 2]) * sstats[ci * 2 + 1], 0.f);
        }
        xin[(ci * 3 + kt) * 256 + hw] = v;
    }
    __syncthreads();

    float accs[8];
    conv_taps(xin, cw, half, bias, accs, tid);
    #pragma unroll
    for (int o = 0; o < 8; ++o) {
        float v = fmaxf(accs[o], 0.f);
        __hip_atomic_store(&y2[((size_t)(b * COUT + half * 8 + o) * TT + t) * 256 + tid],
                           v, __ATOMIC_RELAXED, __HIP_MEMORY_SCOPE_AGENT);
    }
    __syncthreads();
    if (tid == 0)
        __hip_atomic_store(&cflags[blk], 1, __ATOMIC_RELAXED, __HIP_MEMORY_SCOPE_AGENT);
}

// ---------------------------------------------------------------------------
// conv3 body: polls conv2 neighbor flags, ATOMIC y2 loads, ATOMIC out3d stores.
// ---------------------------------------------------------------------------
__device__ __forceinline__
void conv3_body(char* smem, int blk,
                const float* __restrict__ y2, const float* __restrict__ cw,
                const float* __restrict__ bias, float* __restrict__ out3d,
                const int* __restrict__ cflags) {
    float* xin = (float*)smem;
    int b = blk >> 6, t = (blk >> 1) & 31, half = blk & 1;
    int tid = threadIdx.x;

    if (tid == 0) {
        #pragma unroll
        for (int dt = -1; dt <= 1; ++dt) {
            int tn = t + dt;
            if ((unsigned)tn >= TT) continue;
            #pragma unroll
            for (int hh = 0; hh < 2; ++hh) {
                const int* f = &cflags[(b << 6) | (tn << 1) | hh];
                while (__hip_atomic_load(f, __ATOMIC_RELAXED,
                                         __HIP_MEMORY_SCOPE_AGENT) == 0)
                    __builtin_amdgcn_s_sleep(1);
            }
        }
    }
    __syncthreads();

    for (int i = tid; i < CIN * 3 * 256; i += 256) {
        int hw = i & 255, r = i >> 8;
        int kt = r % 3, ci = r / 3;
        int tt = t + kt - 1;
        float v = 0.f;
        if ((unsigned)tt < TT)
            v = __hip_atomic_load(&y2[((size_t)(b * CIN + ci) * TT + tt) * 256 + hw],
                                  __ATOMIC_RELAXED, __HIP_MEMORY_SCOPE_AGENT);
        xin[(ci * 3 + kt) * 256 + hw] = v;
    }
    __syncthreads();

    float accs[8];
    conv_taps(xin, cw, half, bias, accs, tid);
    #pragma unroll
    for (int o = 0; o < 8; ++o)
        __hip_atomic_store(&out3d[((size_t)(b * COUT + half * 8 + o) * TT + t) * 256 + tid],
                           fmaxf(accs[o], 0.f),
                           __ATOMIC_RELAXED, __HIP_MEMORY_SCOPE_AGENT);
}

// ---------------------------------------------------------------------------
// persist body: R-stage -> gx-flag wait -> 32-step recurrence -> combine.
// ---------------------------------------------------------------------------
__device__ __forceinline__
void persist_body(char* smem, int pb,
                  const float* __restrict__ R, const float* __restrict__ Gx,
                  unsigned* __restrict__ hfr, int* __restrict__ flags,
                  const int* __restrict__ gxflags, const int* __restrict__ c3done,
                  const float* __restrict__ out3d,
                  const float* __restrict__ attn_w, const float* __restrict__ attn_b,
                  float* __restrict__ out) {
    ushort_t* Rl = (ushort_t*)smem;                 // [4][32][512] = 128 KB
    float* gh_p  = (float*)(smem + 131072);         // [4][4][16][8] = 8 KB

    int tid  = threadIdx.x;
    int lane = tid & 63;
    int w    = tid >> 6;
    int head = pb >> 6;
    int oc   = pb & 63;

    // ---- stage R slice fp32 -> bf16 LDS in fragment order (no deps) ----
    #pragma unroll 4
    for (int n = 0; n < 64; ++n) {
        int g = n >> 4, r = n & 15;
        const float* src = R + ((size_t)((head * 4 + g) * DH + oc * 16 + r)) * DH + tid * 4;
        f32x4 f = *(const f32x4*)src;
        int k0 = tid * 4;
        int ks = k0 >> 5;
        int kI = (k0 >> 3) & 3;
        int e8 = k0 & 7;
        union { ushort_t u[4]; u64_t q; } pk;
        #pragma unroll
        for (int e = 0; e < 4; ++e) pk.u[e] = f2bf(f[e]);
        *(u64_t*)&Rl[((g * 32 + ks) << 9) + ((kI << 4) | r) * 8 + e8] = pk.q;
    }

    // ---- wait for the 4 GEMM blocks owning our Gx columns ----
    {
        for (;;) {
            int v = 1;
            if (lane < 4)
                v = __hip_atomic_load(&gxflags[lane * 64 + head * 16 + (oc >> 2)],
                                      __ATOMIC_RELAXED, __HIP_MEMORY_SCOPE_AGENT);
            if (__all(v != 0)) break;
            __builtin_amdgcn_s_sleep(1);
        }
    }

    int arow = lane & 15;
    int part = arow >> 3;
    int bb   = arow & 7;
    int kseg = lane >> 4;

    int gb  = tid >> 4;
    int gol = tid & 15;
    int gd  = head * DH + oc * 16 + gol;
    int o_h = oc * 16 + gol;
    unsigned hslot = ((unsigned)head * 32 + (o_h >> 5)) * 256 + gb * 32 + (o_h & 31);
    float c_r = 0.f, n_r = 0.f, m_r = 0.f;

    __syncthreads();

    for (int t = 0; t < TT; ++t) {
        float gx0 = 0.f, gx1 = 0.f, gx2 = 0.f, gx3 = 0.f;
        if (tid < 128) {
            size_t gxoff = ((size_t)(gb * TT + t)) * (4 * DOUT) + gd;
            gx0 = __hip_atomic_load(&Gx[gxoff],            __ATOMIC_RELAXED, __HIP_MEMORY_SCOPE_AGENT);
            gx1 = __hip_atomic_load(&Gx[gxoff + DOUT],     __ATOMIC_RELAXED, __HIP_MEMORY_SCOPE_AGENT);
            gx2 = __hip_atomic_load(&Gx[gxoff + 2 * DOUT], __ATOMIC_RELAXED, __HIP_MEMORY_SCOPE_AGENT);
            gx3 = __hip_atomic_load(&Gx[gxoff + 3 * DOUT], __ATOMIC_RELAXED, __HIP_MEMORY_SCOPE_AGENT);
        }

        if (t > 0) {
            const int* fl = flags + (((t - 1) * 4 + head) << 6);
            for (;;) {
                int v = __hip_atomic_load(fl + lane, __ATOMIC_RELAXED,
                                          __HIP_MEMORY_SCOPE_AGENT);
                if (__all(v != 0)) break;
                __builtin_amdgcn_s_sleep(1);
            }

            const u64_t* hb = (const u64_t*)hfr
                + ((((size_t)(t - 1) * 4 + head) * 32) * 256 + bb * 32 + kseg * 8) / 2;
            bf16x8 hf[8];
            #pragma unroll
            for (int j = 0; j < 8; ++j) {
                const u64_t* p = hb + (size_t)(w * 8 + j) * 128;
                union { ushort_t u[8]; bf16x8 v; } fr;
                #pragma unroll
                for (int e2 = 0; e2 < 4; ++e2) {
                    u64_t q = __hip_atomic_load(p + e2, __ATOMIC_RELAXED,
                                                __HIP_MEMORY_SCOPE_AGENT);
                    unsigned q0 = (unsigned)q, q1 = (unsigned)(q >> 32);
                    fr.u[e2 * 2]     = part ? (ushort_t)(q0 >> 16) : (ushort_t)(q0 & 0xffffu);
                    fr.u[e2 * 2 + 1] = part ? (ushort_t)(q1 >> 16) : (ushort_t)(q1 & 0xffffu);
                }
                hf[j] = fr.v;
            }

            f32x4 acc[4];
            #pragma unroll
            for (int g = 0; g < 4; ++g) acc[g] = (f32x4){0.f, 0.f, 0.f, 0.f};
            #pragma unroll
            for (int g = 0; g < 4; ++g)
                #pragma unroll
                for (int j = 0; j < 8; ++j) {
                    bf16x8 a = *(const bf16x8*)&Rl[((g * 32 + w * 8 + j) << 9) + lane * 8];
                    acc[g] = __builtin_amdgcn_mfma_f32_16x16x32_bf16(a, hf[j], acc[g], 0, 0, 0);
                }
            #pragma unroll
            for (int g = 0; g < 4; ++g)
                #pragma unroll
                for (int r = 0; r < 4; ++r)
                    acc[g][r] += __shfl_xor(acc[g][r], 8, 64);
            if (part == 0) {
                int orow0 = kseg * 4;
                #pragma unroll
                for (int g = 0; g < 4; ++g)
                    #pragma unroll
                    for (int r = 0; r < 4; ++r)
                        gh_p[(((w * 4 + g) * 16 + orow0 + r) << 3) + bb] = acc[g][r];
            }
        } else {
            for (int i = tid; i < 4 * 4 * 16 * 8; i += 256)
                gh_p[i] = 0.f;
        }
        __syncthreads();

        if (tid < 128) {
            float ip = gx0 +
                gh_p[(((0 * 4 + 0) * 16 + gol) << 3) + gb] + gh_p[(((1 * 4 + 0) * 16 + gol) << 3) + gb] +
                gh_p[(((2 * 4 + 0) * 16 + gol) << 3) + gb] + gh_p[(((3 * 4 + 0) * 16 + gol) << 3) + gb];
            float fp = gx1 +
                gh_p[(((0 * 4 + 1) * 16 + gol) << 3) + gb] + gh_p[(((1 * 4 + 1) * 16 + gol) << 3) + gb] +
                gh_p[(((2 * 4 + 1) * 16 + gol) << 3) + gb] + gh_p[(((3 * 4 + 1) * 16 + gol) << 3) + gb];
            float zp = gx2 +
                gh_p[(((0 * 4 + 2) * 16 + gol) << 3) + gb] + gh_p[(((1 * 4 + 2) * 16 + gol) << 3) + gb] +
                gh_p[(((2 * 4 + 2) * 16 + gol) << 3) + gb] + gh_p[(((3 * 4 + 2) * 16 + gol) << 3) + gb];
            float op = gx3 +
                gh_p[(((0 * 4 + 3) * 16 + gol) << 3) + gb] + gh_p[(((1 * 4 + 3) * 16 + gol) << 3) + gb] +
                gh_p[(((2 * 4 + 3) * 16 + gol) << 3) + gb] + gh_p[(((3 * 4 + 3) * 16 + gol) << 3) + gb];
            float mn = fmaxf(fp + m_r, ip);
            float iv = __expf(ip - mn);
            float fv = __expf(fp + m_r - mn);
            float zc = fminf(fmaxf(zp, -9.f), 9.f);
            float th = 1.f - 2.f / (__expf(2.f * zc) + 1.f);
            c_r = fv * c_r + iv * th;
            n_r = fv * n_r + iv;
            float sig = 1.f / (1.f + __expf(-op));
            float hv = sig * c_r / n_r;
            m_r = mn;
            unsigned hi = f2bf(hv);
            unsigned lo = f2bf(hv - bf2f((ushort_t)hi));
            __hip_atomic_store(&hfr[(size_t)t * 32768 + hslot],
                               hi | (lo << 16),
                               __ATOMIC_RELAXED, __HIP_MEMORY_SCOPE_AGENT);
        }
        __syncthreads();
        if (tid == 0)
            __hip_atomic_store(&flags[((t * 4 + head) << 6) + oc], 1,
                               __ATOMIC_RELAXED, __HIP_MEMORY_SCOPE_AGENT);
    }

    // ---- combine epilogue ----
    {
        const int* fl31 = flags + ((31 * 4) << 6);
        for (;;) {
            int ok = 1;
            #pragma unroll
            for (int q = 0; q < 4; ++q)
                ok &= (__hip_atomic_load(fl31 + q * 64 + lane, __ATOMIC_RELAXED,
                                         __HIP_MEMORY_SCOPE_AGENT) != 0);
            if (__all(ok)) break;
            __builtin_amdgcn_s_sleep(1);
        }
        if (tid == 0) {
            while (__hip_atomic_load(c3done, __ATOMIC_RELAXED,
                                     __HIP_MEMORY_SCOPE_AGENT) < 512)
                __builtin_amdgcn_s_sleep(1);
        }
        __syncthreads();

        int idx = pb * 256 + tid;
        int hw = idx & 255;
        int tC = (idx >> 8) & 31;
        int bC = idx >> 13;
        float dot = attn_b[0];
        float sv[16], ov[16];
        #pragma unroll
        for (int ch = 0; ch < 16; ++ch) {
            int d = ch * 256 + hw;
            int hd2 = d >> 10, o_h2 = d & 1023;
            size_t slot = (size_t)tC * 32768 + (size_t)hd2 * 8192
                        + (o_h2 >> 5) * 256 + bC * 32 + (o_h2 & 31);
            unsigned v32 = __hip_atomic_load(&hfr[slot], __ATOMIC_RELAXED,
                                             __HIP_MEMORY_SCOPE_AGENT);
            float s = bf2f((ushort_t)(v32 & 0xffffu)) + bf2f((ushort_t)(v32 >> 16));
            float o3 = __hip_atomic_load(&out3d[(((size_t)(bC * COUT + ch) * TT + tC)) * 256 + hw],
                                         __ATOMIC_RELAXED, __HIP_MEMORY_SCOPE_AGENT);
            sv[ch] = s; ov[ch] = o3;
            dot += attn_w[ch] * s + attn_w[16 + ch] * o3;
        }
        float alpha = 1.f / (1.f + expf(-dot));
        #pragma unroll
        for (int ch = 0; ch < 16; ++ch) {
            out[(((size_t)(bC * COUT + ch) * TT + tC)) * 256 + hw] =
                alpha * ov[ch] + (1.f - alpha) * sv[ch];
        }
    }
}

// ---------------------------------------------------------------------------
// fused1: [0,64) pre-projection GEMM (BN=64); [64,576) conv1+psum
// dyn LDS = 81920 B (2 blocks/CU)
// ---------------------------------------------------------------------------
__global__ __launch_bounds__(256, 2)
void fused1_kernel(const ushort_t* __restrict__ xt, const float* __restrict__ pre_w,
                   const float* __restrict__ pre_b, ushort_t* __restrict__ xs2b,
                   const float* __restrict__ x, const float* __restrict__ cw1,
                   const float* __restrict__ c1_b, float* __restrict__ y1,
                   float* __restrict__ psum) {
    extern __shared__ char smem[];
    if (blockIdx.x < 64)
        gemm_body<64, 64, true, false>(smem, blockIdx.x, xt, pre_w, pre_b, xs2b, DOUT, DIN);
    else
        conv1_body(smem, blockIdx.x - 64, x, cw1, c1_b, y1, psum);
}

// ---------------------------------------------------------------------------
// mega: [0,256) Gx GEMM (atomic out + gxflags); [256,768) conv2;
// [768,1280) conv3 (+ c3done); [1280,1536) persist+combine.
// dyn LDS = 139264 B (1 block/CU)
// ---------------------------------------------------------------------------
__global__ __launch_bounds__(256, 1)
void mega_kernel(const ushort_t* __restrict__ xs2b, const float* __restrict__ lstm_W,
                 const float* __restrict__ lstm_b, float* __restrict__ Gx,
                 int* __restrict__ gxflags,
                 const float* __restrict__ y1, const float* __restrict__ cw2,
                 const float* __restrict__ c2_b, const float* __restrict__ psum,
                 float* __restrict__ y2, int* __restrict__ cflags,
                 const float* __restrict__ cw3, const float* __restrict__ c3_b,
                 float* __restrict__ out3d, int* __restrict__ c3done,
                 const float* __restrict__ R, unsigned* __restrict__ hfr,
                 int* __restrict__ flags,
                 const float* __restrict__ attn_w, const float* __restrict__ attn_b,
                 float* __restrict__ out) {
    extern __shared__ char smem[];
    int bid = blockIdx.x;
    if (bid < 256) {
        gemm_body<64, 64, false, true>(smem, bid, xs2b, lstm_W, lstm_b, Gx, 4 * DOUT, DOUT);
        __syncthreads();   // drain C stores before signal
        if (threadIdx.x == 0)
            __hip_atomic_store(&gxflags[bid], 1, __ATOMIC_RELAXED, __HIP_MEMORY_SCOPE_AGENT);
    } else if (bid < 768) {
        conv2_body(smem, bid - 256, y1, cw2, c2_b, psum, y2, cflags);
    } else if (bid < 1280) {
        conv3_body(smem, bid - 768, y2, cw3, c3_b, out3d, cflags);
        __syncthreads();   // drain out3d stores before counting done
        if (threadIdx.x == 0)
            __hip_atomic_fetch_add(c3done, 1, __ATOMIC_RELAXED, __HIP_MEMORY_SCOPE_AGENT);
    } else {
        persist_body(smem, bid - 1280, R, Gx, hfr, flags, gxflags, c3done,
                     out3d, attn_w, attn_b, out);
    }
}

// ---------------------------------------------------------------------------
extern "C" void kernel_launch(void* const* d_in, const int* in_sizes, int n_in,
                              void* d_out, int out_size, void* d_ws, size_t ws_size,
                              hipStream_t stream) {
    const float* x      = (const float*)d_in[0];
    const float* c1_w   = (const float*)d_in[1];
    const float* c1_b   = (const float*)d_in[2];
    const float* c2_w   = (const float*)d_in[3];
    const float* c2_b   = (const float*)d_in[4];
    const float* c3_w   = (const float*)d_in[5];
    const float* c3_b   = (const float*)d_in[6];
    const float* pre_w  = (const float*)d_in[7];
    const float* pre_b  = (const float*)d_in[8];
    const float* lstm_W = (const float*)d_in[9];
    const float* lstm_b = (const float*)d_in[10];
    const float* lstm_R = (const float*)d_in[11];
    const float* attn_w = (const float*)d_in[12];
    const float* attn_b = (const float*)d_in[13];
    float* out = (float*)d_out;

    // workspace carve (all 16B aligned)
    float* wsf = (float*)d_ws;
    float* y1    = wsf;                // 1048576 f32
    float* y2    = y1 + 1048576;       // 1048576 f32
    float* out3d = y2 + 1048576;       // 1048576 f32
    float* Gx    = out3d + 1048576;    // 4194304 f32
    float* cw1   = Gx + 4194304;       // 6912 f32
    float* cw2   = cw1 + 6912;         // 6912 f32
    float* cw3   = cw2 + 6912;         // 6912 f32
    float* psum  = cw3 + 6912;         // 8192 f32
    float* pad   = psum + 8192;
    ushort_t* xt   = (ushort_t*)(pad + 64);       // 1048576 bf16
    ushort_t* xs2b = xt + 1048576;                // 1048576 bf16
    unsigned* hfr  = (unsigned*)(xs2b + 1048576); // 1048576 u32 (4 MB)
    int*     flags = (int*)(hfr + 1048576);       // 8192 persist
    int*    cflags = flags + 8192;                // 512 conv
    int*   gxflags = cflags + 512;                // 256 gemm
    int*    c3done = gxflags + 256;               // 1 (+pad to 8964)

    // setup: pack xt + pack conv weights + zero all flags (one dispatch)
    setup_kernel<<<1114, 256, 0, stream>>>(x, xt, c1_w, c2_w, c3_w, cw1, cw2, cw3, flags);

    // fused1: pre-projection GEMM BN=64 (64 blk) || conv1+psum (512 blk)
    fused1_kernel<<<576, 256, 81920, stream>>>(xt, pre_w, pre_b, xs2b,
                                               x, cw1, c1_b, y1, psum);

    // mega: Gx GEMM || conv2 || conv3 || persist+combine (flag-chained)
    mega_kernel<<<1536, 256, 139264, stream>>>(xs2b, lstm_W, lstm_b, Gx, gxflags,
                                               y1, cw2, c2_b, psum, y2, cflags,
                                               cw3, c3_b, out3d, c3done,
                                               lstm_R, hfr, flags,
                                               attn_w, attn_b, out);
}

// Round 21
// 525.934 us; speedup vs baseline: 1.2390x; 1.2390x over previous
//
#include <hip/hip_runtime.h>
#include <hip/hip_bf16.h>
#include <cstddef>

// Problem constants
#define BB   8
#define CIN  16
#define COUT 16
#define TT   32
#define HH   16
#define WW   16
#define DIN  4096
#define DOUT 4096
#define NH   4
#define DH   1024
#define SPAT 8192            // T*H*W
#define NSEQ 256             // B*T

typedef __attribute__((ext_vector_type(8))) short  bf16x8;
typedef __attribute__((ext_vector_type(4))) float  f32x4;
typedef __attribute__((ext_vector_type(4))) unsigned short us4;
typedef __attribute__((ext_vector_type(4))) int    i32x4;
typedef unsigned short ushort_t;
typedef unsigned long long u64_t;

static __device__ __forceinline__ ushort_t f2bf(float f) {
    union { float f; unsigned u; } v; v.f = f;
    unsigned r = (v.u + 0x7fffu + ((v.u >> 16) & 1u)) >> 16;
    return (ushort_t)r;
}
static __device__ __forceinline__ float bf2f(ushort_t u) {
    union { unsigned u; float f; } v; v.u = ((unsigned)u) << 16;
    return v.f;
}

// ---------------------------------------------------------------------------
// setup: pack x -> xt (bf16 seq layout) | pack 3 conv weight sets | zero flags
// grid 1114 blocks x 256
// ---------------------------------------------------------------------------
__global__ void setup_kernel(const float* __restrict__ x, ushort_t* __restrict__ xt,
                             const float* __restrict__ w1, const float* __restrict__ w2,
                             const float* __restrict__ w3,
                             float* __restrict__ cw1, float* __restrict__ cw2,
                             float* __restrict__ cw3, int* __restrict__ flags) {
    int bid = blockIdx.x;
    if (bid < 1024) {
        int idx = bid * 256 + threadIdx.x;
        int n = idx >> 10, k4 = (idx & 1023) * 4;
        int b = n >> 5, t = n & 31, c = k4 >> 8, hw = k4 & 255;
        f32x4 f = *(const f32x4*)&x[(((size_t)(b * CIN + c) * TT + t)) * 256 + hw];
        us4 o;
        #pragma unroll
        for (int i = 0; i < 4; ++i) o[i] = f2bf(f[i]);
        *(us4*)&xt[(size_t)n * DIN + k4] = o;
    } else if (bid < 1105) {
        int i = (bid - 1024) * 256 + threadIdx.x;
        if (i < 3 * 6912) {
            int set = i / 6912, j = i - set * 6912;
            const float* w = (set == 0) ? w1 : (set == 1) ? w2 : w3;
            float* cw      = (set == 0) ? cw1 : (set == 1) ? cw2 : cw3;
            int o = j & 15, r = j >> 4;
            int k = r % 27, ci = r / 27;
            cw[j] = w[(size_t)(o * CIN + ci) * 27 + k];
        }
    } else {
        int j = (bid - 1105) * 256 + threadIdx.x;   // int4 each
        if (j < 2176)   // 8192 persist flags + 512 conv flags
            ((i32x4*)flags)[j] = (i32x4){0, 0, 0, 0};
    }
}

// ---------------------------------------------------------------------------
// GEMM body (device fn, dynamic LDS): C[256][N] = A[256][K](bf16) * B^T(fp32)
// BM=256, BN/BK template; 4 waves, dbuf.  Full K (no split).
// ---------------------------------------------------------------------------
template<int BN, int BK, bool OUT_BF16>
__device__ __forceinline__
void gemm_body(char* smem, int bx,
               const ushort_t* __restrict__ A, const float* __restrict__ B,
               const float* __restrict__ bias, void* __restrict__ C,
               int N, int K) {
    constexpr int NF  = BN / 16;
    constexpr int TPR = 256 / BN;
    constexpr int FPT = BK / TPR;
    ushort_t* Al = (ushort_t*)smem;                 // [2][256][BK]
    ushort_t* Bl = Al + 2 * 256 * BK;               // [2][BN][BK]
    int tid  = threadIdx.x;
    int lane = tid & 63;
    int wv   = tid >> 6;
    int n0 = bx * BN;

    f32x4 acc[4][NF];
    #pragma unroll
    for (int i = 0; i < 4; ++i)
        #pragma unroll
        for (int j = 0; j < NF; ++j) acc[i][j] = (f32x4){0.f, 0.f, 0.f, 0.f};

    auto stageA = [&](int buf, int k0) {
        #pragma unroll
        for (int q = 0; q < 8; ++q) {
            int rbase = wv * 64 + q * 8;
            int row = rbase + (lane >> 3);
            const ushort_t* g = A + (size_t)row * K + k0 + (lane & 7) * 8;
            __builtin_amdgcn_global_load_lds(
                (const __attribute__((address_space(1))) void*)g,
                (__attribute__((address_space(3))) void*)&Al[(buf * 256 + rbase) * BK],
                16, 0, 0);
        }
    };
    auto stageB = [&](int buf, int k0) {
        int r  = tid / TPR;
        int cs = (tid % TPR) * FPT;
        const float* g = B + (size_t)(n0 + r) * K + k0 + cs;
        #pragma unroll
        for (int q = 0; q < FPT / 4; ++q) {
            f32x4 f = *(const f32x4*)(g + q * 4);
            us4 pk;
            #pragma unroll
            for (int e = 0; e < 4; ++e) pk[e] = f2bf(f[e]);
            *(us4*)&Bl[(buf * BN + r) * BK + cs + q * 4] = pk;
        }
    };
    auto compute = [&](int buf) {
        #pragma unroll
        for (int ks = 0; ks < BK / 32; ++ks) {
            bf16x8 af[4], bfr[NF];
            #pragma unroll
            for (int i = 0; i < 4; ++i)
                af[i] = *(const bf16x8*)&Al[(buf * 256 + wv * 64 + i * 16 + (lane & 15)) * BK + ks * 32 + (lane >> 4) * 8];
            #pragma unroll
            for (int j = 0; j < NF; ++j)
                bfr[j] = *(const bf16x8*)&Bl[(buf * BN + j * 16 + (lane & 15)) * BK + ks * 32 + (lane >> 4) * 8];
            #pragma unroll
            for (int i = 0; i < 4; ++i)
                #pragma unroll
                for (int j = 0; j < NF; ++j)
                    acc[i][j] = __builtin_amdgcn_mfma_f32_16x16x32_bf16(af[i], bfr[j], acc[i][j], 0, 0, 0);
        }
    };

    stageA(0, 0); stageB(0, 0);
    __syncthreads();
    int nk = K / BK;
    int cur = 0;
    for (int t = 0; t < nk; ++t) {
        if (t + 1 < nk) { stageA(cur ^ 1, (t + 1) * BK); stageB(cur ^ 1, (t + 1) * BK); }
        compute(cur);
        __syncthreads();
        cur ^= 1;
    }

    #pragma unroll
    for (int i = 0; i < 4; ++i) {
        int row = wv * 64 + i * 16 + (lane >> 4) * 4;
        #pragma unroll
        for (int j = 0; j < NF; ++j) {
            int col = n0 + j * 16 + (lane & 15);
            float bv = bias[col];
            #pragma unroll
            for (int r = 0; r < 4; ++r) {
                float v = acc[i][j][r] + bv;
                if constexpr (OUT_BF16) ((ushort_t*)C)[(size_t)(row + r) * N + col] = f2bf(v);
                else                    ((float*)C)[(size_t)(row + r) * N + col] = v;
            }
        }
    }
}

// ---------------------------------------------------------------------------
// conv tap loop (shared)
// ---------------------------------------------------------------------------
__device__ __forceinline__
void conv_taps(const float* xin, const float* __restrict__ cw, int half,
               const float* __restrict__ bias, float* accs, int tid) {
    int h = tid >> 4, wx = tid & 15;
    f32x4 a0 = *(const f32x4*)&bias[half * 8];
    f32x4 a1 = *(const f32x4*)&bias[half * 8 + 4];
    for (int ci = 0; ci < CIN; ++ci) {
        #pragma unroll
        for (int kt = 0; kt < 3; ++kt) {
            #pragma unroll
            for (int kh = 0; kh < 3; ++kh) {
                int h2 = h + kh - 1;
                bool vh = (unsigned)h2 < HH;
                int h2c = vh ? h2 : 0;
                #pragma unroll
                for (int kw = 0; kw < 3; ++kw) {
                    int w2 = wx + kw - 1;
                    bool v = vh && ((unsigned)w2 < WW);
                    int w2c = ((unsigned)w2 < WW) ? w2 : 0;
                    float xv = xin[(ci * 3 + kt) * 256 + h2c * 16 + w2c];
                    xv = v ? xv : 0.f;
                    const float* wp = cw + (size_t)(ci * 27 + kt * 9 + kh * 3 + kw) * 16 + half * 8;
                    f32x4 w0 = *(const f32x4*)(wp);
                    f32x4 w1 = *(const f32x4*)(wp + 4);
                    a0 += xv * w0; a1 += xv * w1;
                }
            }
        }
    }
    #pragma unroll
    for (int i = 0; i < 4; ++i) { accs[i] = a0[i]; accs[4 + i] = a1[i]; }
}

// ---------------------------------------------------------------------------
// conv1 body: plain loads/stores + psum emission
// ---------------------------------------------------------------------------
__device__ __forceinline__
void conv1_body(char* smem, int blk,
                const float* __restrict__ in, const float* __restrict__ cw,
                const float* __restrict__ bias,
                float* __restrict__ out, float* __restrict__ psum) {
    float* xin = (float*)smem;
    int b = blk >> 6, t = (blk >> 1) & 31, half = blk & 1;
    int tid = threadIdx.x;

    for (int i = tid; i < CIN * 3 * 256; i += 256) {
        int hw = i & 255, r = i >> 8;
        int kt = r % 3, ci = r / 3;
        int tt = t + kt - 1;
        float v = 0.f;
        if ((unsigned)tt < TT)
            v = in[((size_t)(b * CIN + ci) * TT + tt) * 256 + hw];
        xin[(ci * 3 + kt) * 256 + hw] = v;
    }
    __syncthreads();

    float accs[8];
    conv_taps(xin, cw, half, bias, accs, tid);
    #pragma unroll
    for (int o = 0; o < 8; ++o)
        out[((size_t)(b * COUT + half * 8 + o) * TT + t) * 256 + tid] = accs[o];

    __syncthreads();
    float* sm = xin;
    int wv = tid >> 6;
    #pragma unroll
    for (int o = 0; o < 8; ++o) {
        float s = accs[o];
        float q = accs[o] * accs[o];
        #pragma unroll
        for (int m = 1; m < 64; m <<= 1) {
            s += __shfl_xor(s, m, 64);
            q += __shfl_xor(q, m, 64);
        }
        if ((tid & 63) == 0) { sm[wv * 16 + o * 2] = s; sm[wv * 16 + o * 2 + 1] = q; }
    }
    __syncthreads();
    if (tid < 16) {
        int o = tid >> 1, which = tid & 1;
        float v = sm[o * 2 + which] + sm[16 + o * 2 + which]
                + sm[32 + o * 2 + which] + sm[48 + o * 2 + which];
        psum[((((size_t)(b * 32 + t) * 2 + half) * 8 + o) * 2) + which] = v;
    }
}

// ---------------------------------------------------------------------------
// conv2 body: in-block stats from psum, inorm+relu at staging, ATOMIC y2
// stores (LLC write-through) + per-(b,t,half) flag signal.
// ---------------------------------------------------------------------------
__device__ __forceinline__
void conv2_body(char* smem, int blk,
                const float* __restrict__ y1, const float* __restrict__ cw,
                const float* __restrict__ bias, const float* __restrict__ psum,
                float* __restrict__ y2, int* __restrict__ cflags) {
    float* xin = (float*)smem;              // 12288 floats
    float* sstats = xin + 12288;            // 32 floats
    int b = blk >> 6, t = (blk >> 1) & 31, half = blk & 1;
    int tid = threadIdx.x;

    if (tid < 16) {
        int c = tid;
        float sum = 0.f, sq = 0.f;
        for (int t2 = 0; t2 < 32; ++t2) {
            size_t base = (((size_t)(b * 32 + t2) * 2 + (c >> 3)) * 8 + (c & 7)) * 2;
            sum += psum[base];
            sq  += psum[base + 1];
        }
        float mu = sum / (float)SPAT;
        float var = sq / (float)SPAT - mu * mu;
        sstats[c * 2]     = mu;
        sstats[c * 2 + 1] = rsqrtf(var + 1e-5f);
    }
    __syncthreads();

    for (int i = tid; i < CIN * 3 * 256; i += 256) {
        int hw = i & 255, r = i >> 8;
        int kt = r % 3, ci = r / 3;
        int tt = t + kt - 1;
        float v = 0.f;
        if ((unsigned)tt < TT) {
            v = y1[((size_t)(b * CIN + ci) * TT + tt) * 256 + hw];
            v = fmaxf((v - sstats[ci * 2]) * sstats[ci * 2 + 1], 0.f);
        }
        xin[(ci * 3 + kt) * 256 + hw] = v;
    }
    __syncthreads();

    float accs[8];
    conv_taps(xin, cw, half, bias, accs, tid);
    #pragma unroll
    for (int o = 0; o < 8; ++o) {
        float v = fmaxf(accs[o], 0.f);
        __hip_atomic_store(&y2[((size_t)(b * COUT + half * 8 + o) * TT + t) * 256 + tid],
                           v, __ATOMIC_RELAXED, __HIP_MEMORY_SCOPE_AGENT);
    }
    __syncthreads();
    if (tid == 0)
        __hip_atomic_store(&cflags[blk], 1, __ATOMIC_RELAXED, __HIP_MEMORY_SCOPE_AGENT);
}

// ---------------------------------------------------------------------------
// conv3 body: polls conv2 neighbor flags, ATOMIC y2 loads, plain out3d stores.
// ---------------------------------------------------------------------------
__device__ __forceinline__
void conv3_body(char* smem, int blk,
                const float* __restrict__ y2, const float* __restrict__ cw,
                const float* __restrict__ bias, float* __restrict__ out3d,
                const int* __restrict__ cflags) {
    float* xin = (float*)smem;
    int b = blk >> 6, t = (blk >> 1) & 31, half = blk & 1;
    int tid = threadIdx.x;

    if (tid == 0) {
        #pragma unroll
        for (int dt = -1; dt <= 1; ++dt) {
            int tn = t + dt;
            if ((unsigned)tn >= TT) continue;
            #pragma unroll
            for (int hh = 0; hh < 2; ++hh) {
                const int* f = &cflags[(b << 6) | (tn << 1) | hh];
                while (__hip_atomic_load(f, __ATOMIC_RELAXED,
                                         __HIP_MEMORY_SCOPE_AGENT) == 0)
                    __builtin_amdgcn_s_sleep(1);
            }
        }
    }
    __syncthreads();

    for (int i = tid; i < CIN * 3 * 256; i += 256) {
        int hw = i & 255, r = i >> 8;
        int kt = r % 3, ci = r / 3;
        int tt = t + kt - 1;
        float v = 0.f;
        if ((unsigned)tt < TT)
            v = __hip_atomic_load(&y2[((size_t)(b * CIN + ci) * TT + tt) * 256 + hw],
                                  __ATOMIC_RELAXED, __HIP_MEMORY_SCOPE_AGENT);
        xin[(ci * 3 + kt) * 256 + hw] = v;
    }
    __syncthreads();

    float accs[8];
    conv_taps(xin, cw, half, bias, accs, tid);
    #pragma unroll
    for (int o = 0; o < 8; ++o)
        out3d[((size_t)(b * COUT + half * 8 + o) * TT + t) * 256 + tid] = fmaxf(accs[o], 0.f);
}

// ---------------------------------------------------------------------------
// fused1: [0,64) pre-projection GEMM (BN=64); [64,576) conv1+psum
// dyn LDS = 81920 B (2 blocks/CU)
// ---------------------------------------------------------------------------
__global__ __launch_bounds__(256, 2)
void fused1_kernel(const ushort_t* __restrict__ xt, const float* __restrict__ pre_w,
                   const float* __restrict__ pre_b, ushort_t* __restrict__ xs2b,
                   const float* __restrict__ x, const float* __restrict__ cw1,
                   const float* __restrict__ c1_b, float* __restrict__ y1,
                   float* __restrict__ psum) {
    extern __shared__ char smem[];
    if (blockIdx.x < 64)
        gemm_body<64, 64, true>(smem, blockIdx.x, xt, pre_w, pre_b, xs2b, DOUT, DIN);
    else
        conv1_body(smem, blockIdx.x - 64, x, cw1, c1_b, y1, psum);
}

// ---------------------------------------------------------------------------
// fused2: [0,256) Gx GEMM (BN=64, full K, bias folded); [256,768) conv2;
// [768,1280) conv3 (flag-chained).  dyn LDS = 81920 B (2 blocks/CU)
// ---------------------------------------------------------------------------
__global__ __launch_bounds__(256, 2)
void fused2_kernel(const ushort_t* __restrict__ xs2b, const float* __restrict__ lstm_W,
                   const float* __restrict__ lstm_b, float* __restrict__ Gx,
                   const float* __restrict__ y1, const float* __restrict__ cw2,
                   const float* __restrict__ c2_b, const float* __restrict__ psum,
                   float* __restrict__ y2,
                   const float* __restrict__ cw3, const float* __restrict__ c3_b,
                   float* __restrict__ out3d, int* __restrict__ cflags) {
    extern __shared__ char smem[];
    if (blockIdx.x < 256)
        gemm_body<64, 64, false>(smem, blockIdx.x, xs2b, lstm_W, lstm_b, Gx, 4 * DOUT, DOUT);
    else if (blockIdx.x < 768)
        conv2_body(smem, blockIdx.x - 256, y1, cw2, c2_b, psum, y2, cflags);
    else
        conv3_body(smem, blockIdx.x - 768, y2, cw3, c3_b, out3d, cflags);
}

// ---------------------------------------------------------------------------
// Persistent sLSTM (R14-proven sync) + combine epilogue.  Gx complete (bias in).
// grid: 256 blocks = head(4) x ochunk(64 of 16 o's), 256 threads, 1 block/CU.
// ---------------------------------------------------------------------------
__global__ __launch_bounds__(256, 1)
void lstm_persist_kernel(const float* __restrict__ R,       // [4][4][1024][1024] fp32
                         const float* __restrict__ Gx,      // [256][16384] complete
                         unsigned* __restrict__ hfr,        // [32][4][32][8][32] u32
                         int* __restrict__ flags,           // [32][4][64], zeroed
                         const float* __restrict__ out3d,
                         const float* __restrict__ attn_w,
                         const float* __restrict__ attn_b,
                         float* __restrict__ out) {
    __shared__ ushort_t Rl[4][32][64 * 8];   // 128 KB
    __shared__ float gh_p[4][4][16][8];      // 8 KB

    int tid  = threadIdx.x;
    int lane = tid & 63;
    int w    = tid >> 6;
    int head = blockIdx.x >> 6;
    int oc   = blockIdx.x & 63;

    // ---- stage R slice fp32 -> bf16 LDS in fragment order, once ----
    #pragma unroll 4
    for (int n = 0; n < 64; ++n) {
        int g = n >> 4, r = n & 15;
        const float* src = R + ((size_t)((head * 4 + g) * DH + oc * 16 + r)) * DH + tid * 4;
        f32x4 f = *(const f32x4*)src;
        int k0 = tid * 4;
        int ks = k0 >> 5;
        int kI = (k0 >> 3) & 3;
        int e8 = k0 & 7;
        union { ushort_t u[4]; u64_t q; } pk;
        #pragma unroll
        for (int e = 0; e < 4; ++e) pk.u[e] = f2bf(f[e]);
        *(u64_t*)&Rl[g][ks][((kI << 4) | r) * 8 + e8] = pk.q;
    }

    int arow = lane & 15;
    int part = arow >> 3;
    int bb   = arow & 7;
    int kseg = lane >> 4;

    int gb  = tid >> 4;
    int gol = tid & 15;
    int gd  = head * DH + oc * 16 + gol;
    int o_h = oc * 16 + gol;
    unsigned hslot = ((unsigned)head * 32 + (o_h >> 5)) * 256 + gb * 32 + (o_h & 31);
    float c_r = 0.f, n_r = 0.f, m_r = 0.f;

    __syncthreads();

    for (int t = 0; t < TT; ++t) {
        float gx0 = 0.f, gx1 = 0.f, gx2 = 0.f, gx3 = 0.f;
        if (tid < 128) {
            size_t gxoff = ((size_t)(gb * TT + t)) * (4 * DOUT) + gd;
            gx0 = Gx[gxoff];
            gx1 = Gx[gxoff + DOUT];
            gx2 = Gx[gxoff + 2 * DOUT];
            gx3 = Gx[gxoff + 3 * DOUT];
        }

        if (t > 0) {
            const int* fl = flags + (((t - 1) * 4 + head) << 6);
            for (;;) {
                int v = __hip_atomic_load(fl + lane, __ATOMIC_RELAXED,
                                          __HIP_MEMORY_SCOPE_AGENT);
                if (__all(v != 0)) break;
                __builtin_amdgcn_s_sleep(1);
            }

            const u64_t* hb = (const u64_t*)hfr
                + ((((size_t)(t - 1) * 4 + head) * 32) * 256 + bb * 32 + kseg * 8) / 2;
            bf16x8 hf[8];
            #pragma unroll
            for (int j = 0; j < 8; ++j) {
                const u64_t* p = hb + (size_t)(w * 8 + j) * 128;
                union { ushort_t u[8]; bf16x8 v; } fr;
                #pragma unroll
                for (int e2 = 0; e2 < 4; ++e2) {
                    u64_t q = __hip_atomic_load(p + e2, __ATOMIC_RELAXED,
                                                __HIP_MEMORY_SCOPE_AGENT);
                    unsigned q0 = (unsigned)q, q1 = (unsigned)(q >> 32);
                    fr.u[e2 * 2]     = part ? (ushort_t)(q0 >> 16) : (ushort_t)(q0 & 0xffffu);
                    fr.u[e2 * 2 + 1] = part ? (ushort_t)(q1 >> 16) : (ushort_t)(q1 & 0xffffu);
                }
                hf[j] = fr.v;
            }

            f32x4 acc[4];
            #pragma unroll
            for (int g = 0; g < 4; ++g) acc[g] = (f32x4){0.f, 0.f, 0.f, 0.f};
            #pragma unroll
            for (int g = 0; g < 4; ++g)
                #pragma unroll
                for (int j = 0; j < 8; ++j) {
                    bf16x8 a = *(const bf16x8*)&Rl[g][w * 8 + j][lane * 8];
                    acc[g] = __builtin_amdgcn_mfma_f32_16x16x32_bf16(a, hf[j], acc[g], 0, 0, 0);
                }
            #pragma unroll
            for (int g = 0; g < 4; ++g)
                #pragma unroll
                for (int r = 0; r < 4; ++r)
                    acc[g][r] += __shfl_xor(acc[g][r], 8, 64);
            if (part == 0) {
                int orow0 = kseg * 4;
                #pragma unroll
                for (int g = 0; g < 4; ++g)
                    #pragma unroll
                    for (int r = 0; r < 4; ++r)
                        gh_p[w][g][orow0 + r][bb] = acc[g][r];
            }
        } else {
            for (int i = tid; i < 4 * 4 * 16 * 8; i += 256)
                ((float*)gh_p)[i] = 0.f;
        }
        __syncthreads();

        if (tid < 128) {
            float ip = gx0 +
                gh_p[0][0][gol][gb] + gh_p[1][0][gol][gb] + gh_p[2][0][gol][gb] + gh_p[3][0][gol][gb];
            float fp = gx1 +
                gh_p[0][1][gol][gb] + gh_p[1][1][gol][gb] + gh_p[2][1][gol][gb] + gh_p[3][1][gol][gb];
            float zp = gx2 +
                gh_p[0][2][gol][gb] + gh_p[1][2][gol][gb] + gh_p[2][2][gol][gb] + gh_p[3][2][gol][gb];
            float op = gx3 +
                gh_p[0][3][gol][gb] + gh_p[1][3][gol][gb] + gh_p[2][3][gol][gb] + gh_p[3][3][gol][gb];
            float mn = fmaxf(fp + m_r, ip);
            float iv = __expf(ip - mn);
            float fv = __expf(fp + m_r - mn);
            float zc = fminf(fmaxf(zp, -9.f), 9.f);
            float th = 1.f - 2.f / (__expf(2.f * zc) + 1.f);
            c_r = fv * c_r + iv * th;
            n_r = fv * n_r + iv;
            float sig = 1.f / (1.f + __expf(-op));
            float hv = sig * c_r / n_r;
            m_r = mn;
            unsigned hi = f2bf(hv);
            unsigned lo = f2bf(hv - bf2f((ushort_t)hi));
            __hip_atomic_store(&hfr[(size_t)t * 32768 + hslot],
                               hi | (lo << 16),
                               __ATOMIC_RELAXED, __HIP_MEMORY_SCOPE_AGENT);
        }
        __syncthreads();
        if (tid == 0)
            __hip_atomic_store(&flags[((t * 4 + head) << 6) + oc], 1,
                               __ATOMIC_RELAXED, __HIP_MEMORY_SCOPE_AGENT);
    }

    // ---- combine epilogue: wait for all final flags, then 1/256 slice
    {
        const int* fl31 = flags + ((31 * 4) << 6);   // 256 contiguous ints
        for (;;) {
            int ok = 1;
            #pragma unroll
            for (int q = 0; q < 4; ++q)
                ok &= (__hip_atomic_load(fl31 + q * 64 + lane, __ATOMIC_RELAXED,
                                         __HIP_MEMORY_SCOPE_AGENT) != 0);
            if (__all(ok)) break;
            __builtin_amdgcn_s_sleep(1);
        }

        int idx = blockIdx.x * 256 + tid;
        int hw = idx & 255;
        int tC = (idx >> 8) & 31;
        int bC = idx >> 13;
        float dot = attn_b[0];
        float sv[16], ov[16];
        #pragma unroll
        for (int ch = 0; ch < 16; ++ch) {
            int d = ch * 256 + hw;
            int hd2 = d >> 10, o_h2 = d & 1023;
            size_t slot = (size_t)tC * 32768 + (size_t)hd2 * 8192
                        + (o_h2 >> 5) * 256 + bC * 32 + (o_h2 & 31);
            unsigned v32 = __hip_atomic_load(&hfr[slot], __ATOMIC_RELAXED,
                                             __HIP_MEMORY_SCOPE_AGENT);
            float s = bf2f((ushort_t)(v32 & 0xffffu)) + bf2f((ushort_t)(v32 >> 16));
            float o3 = out3d[(((size_t)(bC * COUT + ch) * TT + tC)) * 256 + hw];
            sv[ch] = s; ov[ch] = o3;
            dot += attn_w[ch] * s + attn_w[16 + ch] * o3;
        }
        float alpha = 1.f / (1.f + expf(-dot));
        #pragma unroll
        for (int ch = 0; ch < 16; ++ch) {
            out[(((size_t)(bC * COUT + ch) * TT + tC)) * 256 + hw] =
                alpha * ov[ch] + (1.f - alpha) * sv[ch];
        }
    }
}

// ---------------------------------------------------------------------------
extern "C" void kernel_launch(void* const* d_in, const int* in_sizes, int n_in,
                              void* d_out, int out_size, void* d_ws, size_t ws_size,
                              hipStream_t stream) {
    const float* x      = (const float*)d_in[0];
    const float* c1_w   = (const float*)d_in[1];
    const float* c1_b   = (const float*)d_in[2];
    const float* c2_w   = (const float*)d_in[3];
    const float* c2_b   = (const float*)d_in[4];
    const float* c3_w   = (const float*)d_in[5];
    const float* c3_b   = (const float*)d_in[6];
    const float* pre_w  = (const float*)d_in[7];
    const float* pre_b  = (const float*)d_in[8];
    const float* lstm_W = (const float*)d_in[9];
    const float* lstm_b = (const float*)d_in[10];
    const float* lstm_R = (const float*)d_in[11];
    const float* attn_w = (const float*)d_in[12];
    const float* attn_b = (const float*)d_in[13];
    float* out = (float*)d_out;

    // workspace carve (all 16B aligned)
    float* wsf = (float*)d_ws;
    float* y1    = wsf;                // 1048576 f32
    float* y2    = y1 + 1048576;       // 1048576 f32
    float* out3d = y2 + 1048576;       // 1048576 f32
    float* Gx    = out3d + 1048576;    // 4194304 f32
    float* cw1   = Gx + 4194304;       // 6912 f32
    float* cw2   = cw1 + 6912;         // 6912 f32
    float* cw3   = cw2 + 6912;         // 6912 f32
    float* psum  = cw3 + 6912;         // 8192 f32
    float* pad   = psum + 8192;
    ushort_t* xt   = (ushort_t*)(pad + 64);       // 1048576 bf16
    ushort_t* xs2b = xt + 1048576;                // 1048576 bf16
    unsigned* hfr  = (unsigned*)(xs2b + 1048576); // 1048576 u32 (4 MB)
    int*     flags = (int*)(hfr + 1048576);       // 8192 persist + 512 conv
    int*    cflags = flags + 8192;

    // setup: pack xt + pack conv weights + zero flags (one dispatch)
    setup_kernel<<<1114, 256, 0, stream>>>(x, xt, c1_w, c2_w, c3_w, cw1, cw2, cw3, flags);

    // fused1: pre-projection GEMM BN=64 (64 blk) || conv1+psum (512 blk)
    fused1_kernel<<<576, 256, 81920, stream>>>(xt, pre_w, pre_b, xs2b,
                                               x, cw1, c1_b, y1, psum);

    // fused2: Gx GEMM BN=64 full-K (256) || conv2 (512) || conv3 (512, chained)
    fused2_kernel<<<1280, 256, 81920, stream>>>(xs2b, lstm_W, lstm_b, Gx,
                                                y1, cw2, c2_b, psum, y2,
                                                cw3, c3_b, out3d, cflags);

    // recurrence + combine epilogue
    lstm_persist_kernel<<<256, 256, 0, stream>>>(lstm_R, Gx, hfr, flags,
                                                 out3d, attn_w, attn_b, out);
}